// Round 1
// baseline (705.202 us; speedup 1.0000x reference)
//
#include <hip/hip_runtime.h>
#include <hip/hip_bf16.h>

// GCN forward: out = spmm(A, relu(spmm(A, x@W1)+b1) @ W2) + b2
// bf16 intermediate pipeline: GEMM1 + GEMM2 via MFMA bf16, H1/AGG/H2 stored bf16.
// R5: gemm2 was latency-bound (223us, VALUBusy 10%, occ 18% — scalar W2 loads,
// 391 blocks). Rewritten as barrier-free MFMA GEMM over W2t bf16 (64x256, padded).
// R6: spmm1 4-deep / spmm2 2-deep gather unroll (latency hiding; theory: SpMM
// loops are gather-latency-bound, not BW-bound).

#define NFEATS 512
#define NHIDS  256
#define NCLS   40
#define NCLSP  64   // H2 padded feature stride (one 128B line per row)

typedef unsigned short ushort_t;
typedef unsigned int uint_t;
typedef __attribute__((ext_vector_type(8))) short frag8;   // 8 bf16 = 16 B
typedef __attribute__((ext_vector_type(4))) float floatx4;

__device__ __forceinline__ ushort_t f2b(float f) {
    uint_t u = __float_as_uint(f);
    uint_t r = (u + 0x7fffu + ((u >> 16) & 1u)) >> 16;   // RNE
    return (ushort_t)r;
}
__device__ __forceinline__ float b2f(ushort_t b) {
    return __uint_as_float((uint_t)b << 16);
}

// ---------------- CSR build ----------------

__global__ void hist_kernel(const int* __restrict__ row, int* __restrict__ cnt, int E) {
    int e = blockIdx.x * blockDim.x + threadIdx.x;
    if (e < E) atomicAdd(&cnt[row[e]], 1);
}

// device-wide exclusive scan of cnt[N] -> row_ptr[N+1]; zeroes cnt.
#define PS_T 256
#define PS_C 4
#define PS_CHUNK (PS_T * PS_C)   // 1024 elements per block

__global__ __launch_bounds__(PS_T) void scan_partial_kernel(const int* __restrict__ cnt,
                                                            int* __restrict__ blockSums, int N) {
    __shared__ int sm[PS_T];
    int t = threadIdx.x;
    int base = blockIdx.x * PS_CHUNK + t * PS_C;
    int s = 0;
    if (base + PS_C <= N) {
        int4 v = *(const int4*)(cnt + base);
        s = v.x + v.y + v.z + v.w;
    } else {
        for (int i = 0; i < PS_C; i++) if (base + i < N) s += cnt[base + i];
    }
    sm[t] = s;
    __syncthreads();
    for (int off = PS_T / 2; off > 0; off >>= 1) {
        if (t < off) sm[t] += sm[t + off];
        __syncthreads();
    }
    if (t == 0) blockSums[blockIdx.x] = sm[0];
}

#define SS_T 128   // must be >= number of scan blocks (98)
__global__ __launch_bounds__(SS_T) void scan_sums_kernel(int* __restrict__ blockSums, int B) {
    __shared__ int sm[SS_T];
    int t = threadIdx.x;
    int v = (t < B) ? blockSums[t] : 0;
    sm[t] = v;
    __syncthreads();
    for (int off = 1; off < SS_T; off <<= 1) {
        int x = (t >= off) ? sm[t - off] : 0;
        __syncthreads();
        sm[t] += x;
        __syncthreads();
    }
    if (t < B) blockSums[t] = sm[t] - v;   // exclusive
}

__global__ __launch_bounds__(PS_T) void scan_finalize_kernel(int* __restrict__ cnt,
                                                             const int* __restrict__ blockSums,
                                                             int* __restrict__ row_ptr, int N, int E) {
    __shared__ int sm[PS_T];
    int t = threadIdx.x;
    int base = blockIdx.x * PS_CHUNK + t * PS_C;
    int vals[PS_C];
    int s = 0;
#pragma unroll
    for (int i = 0; i < PS_C; i++) {
        int idx = base + i;
        vals[i] = (idx < N) ? cnt[idx] : 0;
        s += vals[i];
    }
    sm[t] = s;
    __syncthreads();
    for (int off = 1; off < PS_T; off <<= 1) {
        int x = (t >= off) ? sm[t - off] : 0;
        __syncthreads();
        sm[t] += x;
        __syncthreads();
    }
    int run = blockSums[blockIdx.x] + sm[t] - s;   // exclusive prefix for this thread
#pragma unroll
    for (int i = 0; i < PS_C; i++) {
        int idx = base + i;
        if (idx < N) {
            row_ptr[idx] = run;
            run += vals[i];
            cnt[idx] = 0;   // reuse as fill counter in scatter
        }
    }
    if (blockIdx.x == 0 && t == 0) row_ptr[N] = E;
}

__global__ void scatter_kernel(const int* __restrict__ row, const int* __restrict__ col,
                               const float* __restrict__ val, const int* __restrict__ row_ptr,
                               int* __restrict__ fill, int2* __restrict__ cv, int E) {
    int e = blockIdx.x * blockDim.x + threadIdx.x;
    if (e < E) {
        int r = row[e];
        int p = row_ptr[r] + atomicAdd(&fill[r], 1);
        cv[p] = make_int2(col[e], __float_as_int(val[e]));
    }
}

// ---------------- weight conversions ----------------

// W1 [512][256] f32 -> W1t [256][512] bf16 (n-major)
__global__ void convert_w1(const float* __restrict__ W1, ushort_t* __restrict__ W1t) {
    int idx = blockIdx.x * 256 + threadIdx.x;   // 131072 total
    int k = idx >> 8, n = idx & 255;
    W1t[n * 512 + k] = f2b(W1[idx]);
}

// W2 [256][40] f32 -> W2t [64][256] bf16 (n-major, rows 40..63 zero)
__global__ void convert_w2(const float* __restrict__ W2, ushort_t* __restrict__ W2t) {
    int idx = blockIdx.x * 256 + threadIdx.x;   // 16384 total
    int n = idx >> 8, k = idx & 255;
    W2t[idx] = (n < NCLS) ? f2b(W2[k * NCLS + n]) : (ushort_t)0;
}

// ---------------- GEMM1: H1 = bf16(x @ W1)  via MFMA ----------------
// tile 64(M) x 256(N), BK=32, 256 threads = 4 waves; wave w covers n = w*64..w*64+63.

#define G1_BM 64
#define G1_BN 256
#define G1_BK 32
#define LDK   40   // padded K-stride (elements); 80 B, 16B-aligned

__global__ __launch_bounds__(256) void gemm1_kernel(const float* __restrict__ A,
                                                    const ushort_t* __restrict__ Bt,
                                                    ushort_t* __restrict__ H1, int M) {
    __shared__ ushort_t As[G1_BM * LDK];   // 5120 B
    __shared__ ushort_t Bs[G1_BN * LDK];   // 20480 B
    int tid  = threadIdx.x;
    int wave = tid >> 6, lane = tid & 63;
    int quad = lane >> 4, ln = lane & 15;
    int m0 = blockIdx.x * G1_BM;

    floatx4 acc[4][4] = {};

    for (int k0 = 0; k0 < NFEATS; k0 += G1_BK) {
#pragma unroll
        for (int i = 0; i < 2; i++) {
            int idx = i * 256 + tid;
            int row = idx >> 3;
            int c4  = idx & 7;
            float4 v = make_float4(0.f, 0.f, 0.f, 0.f);
            int gr = m0 + row;
            if (gr < M) v = *(const float4*)(A + (size_t)gr * NFEATS + k0 + c4 * 4);
            ushort4 b;
            b.x = f2b(v.x); b.y = f2b(v.y); b.z = f2b(v.z); b.w = f2b(v.w);
            *(ushort4*)&As[row * LDK + c4 * 4] = b;
        }
#pragma unroll
        for (int i = 0; i < 4; i++) {
            int idx = i * 256 + tid;
            int n  = idx >> 2;
            int k8 = idx & 3;
            uint4 v = *(const uint4*)(Bt + (size_t)n * 512 + k0 + k8 * 8);
            *(uint4*)&Bs[n * LDK + k8 * 8] = v;
        }
        __syncthreads();
        frag8 af[4], bf[4];
#pragma unroll
        for (int t = 0; t < 4; t++)
            af[t] = *(const frag8*)&As[(t * 16 + ln) * LDK + quad * 8];
#pragma unroll
        for (int t = 0; t < 4; t++)
            bf[t] = *(const frag8*)&Bs[(wave * 64 + t * 16 + ln) * LDK + quad * 8];
#pragma unroll
        for (int mt = 0; mt < 4; mt++)
#pragma unroll
            for (int nt = 0; nt < 4; nt++)
                acc[mt][nt] = __builtin_amdgcn_mfma_f32_16x16x32_bf16(af[mt], bf[nt], acc[mt][nt], 0, 0, 0);
        __syncthreads();
    }
#pragma unroll
    for (int mt = 0; mt < 4; mt++) {
#pragma unroll
        for (int i = 0; i < 4; i++) {
            int m = m0 + mt * 16 + quad * 4 + i;
            if (m < M) {
#pragma unroll
                for (int nt = 0; nt < 4; nt++) {
                    H1[(size_t)m * NHIDS + wave * 64 + nt * 16 + ln] = f2b(acc[mt][nt][i]);
                }
            }
        }
    }
}

// ---------------- SpMM1: AGG = bf16(relu(A_hat @ H1 + b1)), F=256 ----------------
// one wave per row; 4-deep gather unroll for memory-level parallelism.

__global__ __launch_bounds__(256) void spmm1_kernel(const int* __restrict__ row_ptr,
                                                    const int2* __restrict__ cv,
                                                    const ushort_t* __restrict__ H1,
                                                    const float* __restrict__ b1,
                                                    ushort_t* __restrict__ AGG, int N) {
    int wave = threadIdx.x >> 6, lane = threadIdx.x & 63;
    int r = blockIdx.x * 4 + wave;
    if (r >= N) return;
    int s = row_ptr[r], e = row_ptr[r + 1];
    float a0 = 0.f, a1 = 0.f, a2 = 0.f, a3 = 0.f;
    int j = s;
    for (; j + 3 < e; j += 4) {
        int2 p0 = cv[j];
        int2 p1 = cv[j + 1];
        int2 p2 = cv[j + 2];
        int2 p3 = cv[j + 3];
        ushort4 h0 = *(const ushort4*)(H1 + (size_t)p0.x * NHIDS + lane * 4);
        ushort4 h1 = *(const ushort4*)(H1 + (size_t)p1.x * NHIDS + lane * 4);
        ushort4 h2 = *(const ushort4*)(H1 + (size_t)p2.x * NHIDS + lane * 4);
        ushort4 h3 = *(const ushort4*)(H1 + (size_t)p3.x * NHIDS + lane * 4);
        float v0 = __int_as_float(p0.y), v1 = __int_as_float(p1.y);
        float v2 = __int_as_float(p2.y), v3 = __int_as_float(p3.y);
        a0 += v0 * b2f(h0.x); a1 += v0 * b2f(h0.y); a2 += v0 * b2f(h0.z); a3 += v0 * b2f(h0.w);
        a0 += v1 * b2f(h1.x); a1 += v1 * b2f(h1.y); a2 += v1 * b2f(h1.z); a3 += v1 * b2f(h1.w);
        a0 += v2 * b2f(h2.x); a1 += v2 * b2f(h2.y); a2 += v2 * b2f(h2.z); a3 += v2 * b2f(h2.w);
        a0 += v3 * b2f(h3.x); a1 += v3 * b2f(h3.y); a2 += v3 * b2f(h3.z); a3 += v3 * b2f(h3.w);
    }
    for (; j < e; j++) {
        int2 p0 = cv[j];
        ushort4 h0 = *(const ushort4*)(H1 + (size_t)p0.x * NHIDS + lane * 4);
        float v0 = __int_as_float(p0.y);
        a0 += v0 * b2f(h0.x); a1 += v0 * b2f(h0.y); a2 += v0 * b2f(h0.z); a3 += v0 * b2f(h0.w);
    }
    float4 bb = *(const float4*)(b1 + lane * 4);
    a0 += bb.x; a1 += bb.y; a2 += bb.z; a3 += bb.w;
    ushort4 o;
    o.x = f2b(a0 > 0.f ? a0 : 0.f);
    o.y = f2b(a1 > 0.f ? a1 : 0.f);
    o.z = f2b(a2 > 0.f ? a2 : 0.f);
    o.w = f2b(a3 > 0.f ? a3 : 0.f);
    *(ushort4*)&AGG[(size_t)r * NHIDS + lane * 4] = o;
}

// ---------------- GEMM2: H2 = bf16(AGG @ W2) via MFMA, padded to 64 cols ----------------
// 256 threads = 4 waves; block covers 256 rows (wave w: rows w*64..w*64+63).
// All 64 output cols per wave = 4 n-tiles; K=256 = 8 chunks of 32. No LDS, no barriers:
// A-frags direct from AGG (16B/lane), B-frags from W2t (32 KB, L1/L2-resident).

__global__ __launch_bounds__(256) void gemm2_kernel(const ushort_t* __restrict__ AGG,
                                                    const ushort_t* __restrict__ W2t,
                                                    ushort_t* __restrict__ H2, int M) {
    int tid  = threadIdx.x;
    int wave = tid >> 6, lane = tid & 63;
    int quad = lane >> 4, ln = lane & 15;
    int m0 = blockIdx.x * 256 + wave * 64;

    floatx4 acc[4][4] = {};
    frag8 zf = {};

#pragma unroll
    for (int k0 = 0; k0 < NHIDS; k0 += 32) {
        frag8 af[4], bf[4];
#pragma unroll
        for (int mt = 0; mt < 4; mt++) {
            int m = m0 + mt * 16 + ln;
            af[mt] = (m < M) ? *(const frag8*)(AGG + (size_t)m * NHIDS + k0 + quad * 8) : zf;
        }
#pragma unroll
        for (int nt = 0; nt < 4; nt++)
            bf[nt] = *(const frag8*)(W2t + (size_t)(nt * 16 + ln) * NHIDS + k0 + quad * 8);
#pragma unroll
        for (int mt = 0; mt < 4; mt++)
#pragma unroll
            for (int nt = 0; nt < 4; nt++)
                acc[mt][nt] = __builtin_amdgcn_mfma_f32_16x16x32_bf16(af[mt], bf[nt], acc[mt][nt], 0, 0, 0);
    }
    // C/D layout: col = ln, row = quad*4 + i
#pragma unroll
    for (int mt = 0; mt < 4; mt++) {
#pragma unroll
        for (int i = 0; i < 4; i++) {
            int m = m0 + mt * 16 + quad * 4 + i;
            if (m < M) {
#pragma unroll
                for (int nt = 0; nt < 4; nt++)
                    H2[(size_t)m * NCLSP + nt * 16 + ln] = f2b(acc[mt][nt][i]);
            }
        }
    }
}

// ---------------- SpMM2: out = A_hat @ H2 + b2, F=40 (padded reads of 64) ----------------
// 2-deep gather unroll.

__global__ __launch_bounds__(256) void spmm2_kernel(const int* __restrict__ row_ptr,
                                                    const int2* __restrict__ cv,
                                                    const ushort_t* __restrict__ H2,
                                                    const float* __restrict__ b2,
                                                    float* __restrict__ out, int N) {
    int wave = threadIdx.x >> 6, lane = threadIdx.x & 63;
    int half = lane >> 5, fl = lane & 31;
    int r = blockIdx.x * 8 + wave * 2 + half;
    if (r >= N) return;
    int s = row_ptr[r], e = row_ptr[r + 1];
    float a0 = 0.f, a1 = 0.f;
    int j = s;
    for (; j + 1 < e; j += 2) {
        int2 p0 = cv[j];
        int2 p1 = cv[j + 1];
        float v0 = __int_as_float(p0.y);
        float v1 = __int_as_float(p1.y);
        uint_t h0 = *(const uint_t*)(H2 + (size_t)p0.x * NCLSP + fl * 2);
        uint_t h1 = *(const uint_t*)(H2 + (size_t)p1.x * NCLSP + fl * 2);
        a0 += v0 * b2f((ushort_t)(h0 & 0xffff));
        a1 += v0 * b2f((ushort_t)(h0 >> 16));
        a0 += v1 * b2f((ushort_t)(h1 & 0xffff));
        a1 += v1 * b2f((ushort_t)(h1 >> 16));
    }
    if (j < e) {
        int2 p = cv[j];
        float v = __int_as_float(p.y);
        uint_t h = *(const uint_t*)(H2 + (size_t)p.x * NCLSP + fl * 2);
        a0 += v * b2f((ushort_t)(h & 0xffff));
        a1 += v * b2f((ushort_t)(h >> 16));
    }
    if (fl < NCLS / 2) {
        float2 o;
        o.x = a0 + b2[fl * 2];
        o.y = a1 + b2[fl * 2 + 1];
        *(float2*)(out + (size_t)r * NCLS + fl * 2) = o;
    }
}

// ---------------- launch ----------------

static inline size_t align256(size_t x) { return (x + 255) & ~(size_t)255; }

extern "C" void kernel_launch(void* const* d_in, const int* in_sizes, int n_in,
                              void* d_out, int out_size, void* d_ws, size_t ws_size,
                              hipStream_t stream) {
    const float* x        = (const float*)d_in[0];
    const float* W1       = (const float*)d_in[1];
    const float* b1       = (const float*)d_in[2];
    const float* W2       = (const float*)d_in[3];
    const float* b2       = (const float*)d_in[4];
    const int*   edge_row = (const int*)d_in[5];
    const int*   edge_col = (const int*)d_in[6];
    const float* edge_val = (const float*)d_in[7];
    float* out = (float*)d_out;

    int N = in_sizes[0] / NFEATS;  // 100000
    int E = in_sizes[5];           // 1700000

    char* w = (char*)d_ws;
    size_t off = 0;
    ushort_t* H1   = (ushort_t*)(w + off); off += align256((size_t)N * NHIDS * 2);
    ushort_t* AGG  = (ushort_t*)(w + off); off += align256((size_t)N * NHIDS * 2);
    ushort_t* H2   = (ushort_t*)(w + off); off += align256((size_t)N * NCLSP * 2);
    ushort_t* W1t  = (ushort_t*)(w + off); off += align256((size_t)NHIDS * NFEATS * 2);
    ushort_t* W2t  = (ushort_t*)(w + off); off += align256((size_t)NCLSP * NHIDS * 2);
    int*      row_ptr = (int*)(w + off); off += align256((size_t)(N + 1) * 4);
    int*      cnt     = (int*)(w + off); off += align256((size_t)N * 4);
    int*      blockSums = (int*)(w + off); off += align256((size_t)SS_T * 4);
    int2*     cv      = (int2*)(w + off); off += align256((size_t)E * 8);

    int scanB = (N + PS_CHUNK - 1) / PS_CHUNK;   // 98 for N=100000 (must be <= SS_T)

    // CSR build + weight conversion
    hipMemsetAsync(cnt, 0, (size_t)N * 4, stream);
    hist_kernel<<<(E + 255) / 256, 256, 0, stream>>>(edge_row, cnt, E);
    convert_w1<<<(NFEATS * NHIDS) / 256, 256, 0, stream>>>(W1, W1t);
    convert_w2<<<(NCLSP * NHIDS) / 256, 256, 0, stream>>>(W2, W2t);
    scan_partial_kernel<<<scanB, PS_T, 0, stream>>>(cnt, blockSums, N);
    scan_sums_kernel<<<1, SS_T, 0, stream>>>(blockSums, scanB);
    scan_finalize_kernel<<<scanB, PS_T, 0, stream>>>(cnt, blockSums, row_ptr, N, E);
    scatter_kernel<<<(E + 255) / 256, 256, 0, stream>>>(edge_row, edge_col, edge_val,
                                                        row_ptr, cnt, cv, E);

    // layer 1
    gemm1_kernel<<<(N + G1_BM - 1) / G1_BM, 256, 0, stream>>>(x, W1t, H1, N);
    spmm1_kernel<<<(N + 3) / 4, 256, 0, stream>>>(row_ptr, cv, H1, b1, AGG, N);

    // layer 2
    gemm2_kernel<<<(N + 255) / 256, 256, 0, stream>>>(AGG, W2t, H2, N);
    spmm2_kernel<<<(N + 7) / 8, 256, 0, stream>>>(row_ptr, cv, H2, b2, out, N);
}

// Round 2
// 697.652 us; speedup vs baseline: 1.0108x; 1.0108x over previous
//
#include <hip/hip_runtime.h>
#include <hip/hip_bf16.h>

// GCN forward: out = spmm(A, relu(spmm(A, x@W1)+b1) @ W2) + b2
// bf16 intermediate pipeline: GEMM1 + GEMM2 via MFMA bf16, H1/AGG/H2 stored bf16.
// R5: gemm2 rewritten barrier-free over L2-resident W2t (was latency-bound).
// R6: spmm 4/2-deep gather unroll. 705us total; gemm1 now largest (131us,
//     MfmaUtil 7.6%, VALUBusy 9.6%, HBM 15% -- latency-bound, 2 barriers/step,
//     no prefetch, 20KB LDS wasted staging L2-resident W1t).
// R7: gemm1 restructured: B direct from L2 (no LDS staging), A double-buffered
//     (2x5KB), next-tile loads issued before MFMAs, one barrier per K-step.

#define NFEATS 512
#define NHIDS  256
#define NCLS   40
#define NCLSP  64   // H2 padded feature stride (one 128B line per row)

typedef unsigned short ushort_t;
typedef unsigned int uint_t;
typedef __attribute__((ext_vector_type(8))) short frag8;   // 8 bf16 = 16 B
typedef __attribute__((ext_vector_type(4))) float floatx4;

__device__ __forceinline__ ushort_t f2b(float f) {
    uint_t u = __float_as_uint(f);
    uint_t r = (u + 0x7fffu + ((u >> 16) & 1u)) >> 16;   // RNE
    return (ushort_t)r;
}
__device__ __forceinline__ float b2f(ushort_t b) {
    return __uint_as_float((uint_t)b << 16);
}

// ---------------- CSR build ----------------

__global__ void hist_kernel(const int* __restrict__ row, int* __restrict__ cnt, int E) {
    int e = blockIdx.x * blockDim.x + threadIdx.x;
    if (e < E) atomicAdd(&cnt[row[e]], 1);
}

// device-wide exclusive scan of cnt[N] -> row_ptr[N+1]; zeroes cnt.
#define PS_T 256
#define PS_C 4
#define PS_CHUNK (PS_T * PS_C)   // 1024 elements per block

__global__ __launch_bounds__(PS_T) void scan_partial_kernel(const int* __restrict__ cnt,
                                                            int* __restrict__ blockSums, int N) {
    __shared__ int sm[PS_T];
    int t = threadIdx.x;
    int base = blockIdx.x * PS_CHUNK + t * PS_C;
    int s = 0;
    if (base + PS_C <= N) {
        int4 v = *(const int4*)(cnt + base);
        s = v.x + v.y + v.z + v.w;
    } else {
        for (int i = 0; i < PS_C; i++) if (base + i < N) s += cnt[base + i];
    }
    sm[t] = s;
    __syncthreads();
    for (int off = PS_T / 2; off > 0; off >>= 1) {
        if (t < off) sm[t] += sm[t + off];
        __syncthreads();
    }
    if (t == 0) blockSums[blockIdx.x] = sm[0];
}

#define SS_T 128   // must be >= number of scan blocks (98)
__global__ __launch_bounds__(SS_T) void scan_sums_kernel(int* __restrict__ blockSums, int B) {
    __shared__ int sm[SS_T];
    int t = threadIdx.x;
    int v = (t < B) ? blockSums[t] : 0;
    sm[t] = v;
    __syncthreads();
    for (int off = 1; off < SS_T; off <<= 1) {
        int x = (t >= off) ? sm[t - off] : 0;
        __syncthreads();
        sm[t] += x;
        __syncthreads();
    }
    if (t < B) blockSums[t] = sm[t] - v;   // exclusive
}

__global__ __launch_bounds__(PS_T) void scan_finalize_kernel(int* __restrict__ cnt,
                                                             const int* __restrict__ blockSums,
                                                             int* __restrict__ row_ptr, int N, int E) {
    __shared__ int sm[PS_T];
    int t = threadIdx.x;
    int base = blockIdx.x * PS_CHUNK + t * PS_C;
    int vals[PS_C];
    int s = 0;
#pragma unroll
    for (int i = 0; i < PS_C; i++) {
        int idx = base + i;
        vals[i] = (idx < N) ? cnt[idx] : 0;
        s += vals[i];
    }
    sm[t] = s;
    __syncthreads();
    for (int off = 1; off < PS_T; off <<= 1) {
        int x = (t >= off) ? sm[t - off] : 0;
        __syncthreads();
        sm[t] += x;
        __syncthreads();
    }
    int run = blockSums[blockIdx.x] + sm[t] - s;   // exclusive prefix for this thread
#pragma unroll
    for (int i = 0; i < PS_C; i++) {
        int idx = base + i;
        if (idx < N) {
            row_ptr[idx] = run;
            run += vals[i];
            cnt[idx] = 0;   // reuse as fill counter in scatter
        }
    }
    if (blockIdx.x == 0 && t == 0) row_ptr[N] = E;
}

__global__ void scatter_kernel(const int* __restrict__ row, const int* __restrict__ col,
                               const float* __restrict__ val, const int* __restrict__ row_ptr,
                               int* __restrict__ fill, int2* __restrict__ cv, int E) {
    int e = blockIdx.x * blockDim.x + threadIdx.x;
    if (e < E) {
        int r = row[e];
        int p = row_ptr[r] + atomicAdd(&fill[r], 1);
        cv[p] = make_int2(col[e], __float_as_int(val[e]));
    }
}

// ---------------- weight conversions ----------------

// W1 [512][256] f32 -> W1t [256][512] bf16 (n-major)
__global__ void convert_w1(const float* __restrict__ W1, ushort_t* __restrict__ W1t) {
    int idx = blockIdx.x * 256 + threadIdx.x;   // 131072 total
    int k = idx >> 8, n = idx & 255;
    W1t[n * 512 + k] = f2b(W1[idx]);
}

// W2 [256][40] f32 -> W2t [64][256] bf16 (n-major, rows 40..63 zero)
__global__ void convert_w2(const float* __restrict__ W2, ushort_t* __restrict__ W2t) {
    int idx = blockIdx.x * 256 + threadIdx.x;   // 16384 total
    int n = idx >> 8, k = idx & 255;
    W2t[idx] = (n < NCLS) ? f2b(W2[k * NCLS + n]) : (ushort_t)0;
}

// ---------------- GEMM1: H1 = bf16(x @ W1)  via MFMA ----------------
// tile 64(M) x 256(N), BK=32, 256 threads = 4 waves; wave w covers n = w*64..w*64+63.
// A double-buffered in LDS (bf16, LDK=40 pad); B read direct from L2-resident W1t.
// One barrier per K-step; next A tile's global loads issued before the MFMAs.

#define G1_BM 64
#define G1_BN 256
#define G1_BK 32
#define G1_NK (NFEATS / G1_BK)   // 16 K-steps
#define LDK   40   // padded K-stride (elements); 80 B, 16B-aligned

__global__ __launch_bounds__(256) void gemm1_kernel(const float* __restrict__ A,
                                                    const ushort_t* __restrict__ Bt,
                                                    ushort_t* __restrict__ H1, int M) {
    __shared__ ushort_t As[2][G1_BM * LDK];   // 2 x 5120 B
    int tid  = threadIdx.x;
    int wave = tid >> 6, lane = tid & 63;
    int quad = lane >> 4, ln = lane & 15;
    int m0 = blockIdx.x * G1_BM;

    // staging coords: thread stages rows {srow, srow+32}, k-chunk sc4 (4 floats each)
    int srow = tid >> 3;          // 0..31
    int sc4  = tid & 7;           // 0..7
    const float* ap0 = A + (size_t)(m0 + srow)      * NFEATS + sc4 * 4;
    const float* ap1 = A + (size_t)(m0 + srow + 32) * NFEATS + sc4 * 4;
    bool ok0 = (m0 + srow)      < M;
    bool ok1 = (m0 + srow + 32) < M;
    float4 z4 = make_float4(0.f, 0.f, 0.f, 0.f);

    // B fragment base for this lane: row (wave*64 + nt*16 + ln), k-offset quad*8
    const ushort_t* bbase = Bt + ((size_t)(wave * 64 + ln) * NFEATS) + quad * 8;

    floatx4 acc[4][4] = {};

    // prologue: stage k-step 0 into As[0]
    {
        float4 v0 = ok0 ? *(const float4*)ap0 : z4;
        float4 v1 = ok1 ? *(const float4*)ap1 : z4;
        ushort4 b0, b1;
        b0.x = f2b(v0.x); b0.y = f2b(v0.y); b0.z = f2b(v0.z); b0.w = f2b(v0.w);
        b1.x = f2b(v1.x); b1.y = f2b(v1.y); b1.z = f2b(v1.z); b1.w = f2b(v1.w);
        *(ushort4*)&As[0][srow * LDK + sc4 * 4]        = b0;
        *(ushort4*)&As[0][(srow + 32) * LDK + sc4 * 4] = b1;
    }
    __syncthreads();

#pragma unroll 2
    for (int t = 0; t < G1_NK; ++t) {
        int cur = t & 1;
        // issue next A tile's global loads first (hide HBM latency under MFMAs)
        float4 n0 = z4, n1 = z4;
        if (t < G1_NK - 1) {
            if (ok0) n0 = *(const float4*)(ap0 + (t + 1) * G1_BK);
            if (ok1) n1 = *(const float4*)(ap1 + (t + 1) * G1_BK);
        }
        // B fragments direct from global (L2-resident, identical across blocks)
        frag8 bfr[4], af[4];
#pragma unroll
        for (int nt = 0; nt < 4; nt++)
            bfr[nt] = *(const frag8*)(bbase + (size_t)nt * 16 * NFEATS + t * G1_BK);
#pragma unroll
        for (int mt = 0; mt < 4; mt++)
            af[mt] = *(const frag8*)&As[cur][(mt * 16 + ln) * LDK + quad * 8];
#pragma unroll
        for (int mt = 0; mt < 4; mt++)
#pragma unroll
            for (int nt = 0; nt < 4; nt++)
                acc[mt][nt] = __builtin_amdgcn_mfma_f32_16x16x32_bf16(af[mt], bfr[nt], acc[mt][nt], 0, 0, 0);
        // convert + write next tile into the other buffer
        if (t < G1_NK - 1) {
            ushort4 b0, b1;
            b0.x = f2b(n0.x); b0.y = f2b(n0.y); b0.z = f2b(n0.z); b0.w = f2b(n0.w);
            b1.x = f2b(n1.x); b1.y = f2b(n1.y); b1.z = f2b(n1.z); b1.w = f2b(n1.w);
            *(ushort4*)&As[cur ^ 1][srow * LDK + sc4 * 4]        = b0;
            *(ushort4*)&As[cur ^ 1][(srow + 32) * LDK + sc4 * 4] = b1;
        }
        __syncthreads();
    }

#pragma unroll
    for (int mt = 0; mt < 4; mt++) {
#pragma unroll
        for (int i = 0; i < 4; i++) {
            int m = m0 + mt * 16 + quad * 4 + i;
            if (m < M) {
#pragma unroll
                for (int nt = 0; nt < 4; nt++) {
                    H1[(size_t)m * NHIDS + wave * 64 + nt * 16 + ln] = f2b(acc[mt][nt][i]);
                }
            }
        }
    }
}

// ---------------- SpMM1: AGG = bf16(relu(A_hat @ H1 + b1)), F=256 ----------------
// one wave per row; 4-deep gather unroll for memory-level parallelism.

__global__ __launch_bounds__(256) void spmm1_kernel(const int* __restrict__ row_ptr,
                                                    const int2* __restrict__ cv,
                                                    const ushort_t* __restrict__ H1,
                                                    const float* __restrict__ b1,
                                                    ushort_t* __restrict__ AGG, int N) {
    int wave = threadIdx.x >> 6, lane = threadIdx.x & 63;
    int r = blockIdx.x * 4 + wave;
    if (r >= N) return;
    int s = row_ptr[r], e = row_ptr[r + 1];
    float a0 = 0.f, a1 = 0.f, a2 = 0.f, a3 = 0.f;
    int j = s;
    for (; j + 3 < e; j += 4) {
        int2 p0 = cv[j];
        int2 p1 = cv[j + 1];
        int2 p2 = cv[j + 2];
        int2 p3 = cv[j + 3];
        ushort4 h0 = *(const ushort4*)(H1 + (size_t)p0.x * NHIDS + lane * 4);
        ushort4 h1 = *(const ushort4*)(H1 + (size_t)p1.x * NHIDS + lane * 4);
        ushort4 h2 = *(const ushort4*)(H1 + (size_t)p2.x * NHIDS + lane * 4);
        ushort4 h3 = *(const ushort4*)(H1 + (size_t)p3.x * NHIDS + lane * 4);
        float v0 = __int_as_float(p0.y), v1 = __int_as_float(p1.y);
        float v2 = __int_as_float(p2.y), v3 = __int_as_float(p3.y);
        a0 += v0 * b2f(h0.x); a1 += v0 * b2f(h0.y); a2 += v0 * b2f(h0.z); a3 += v0 * b2f(h0.w);
        a0 += v1 * b2f(h1.x); a1 += v1 * b2f(h1.y); a2 += v1 * b2f(h1.z); a3 += v1 * b2f(h1.w);
        a0 += v2 * b2f(h2.x); a1 += v2 * b2f(h2.y); a2 += v2 * b2f(h2.z); a3 += v2 * b2f(h2.w);
        a0 += v3 * b2f(h3.x); a1 += v3 * b2f(h3.y); a2 += v3 * b2f(h3.z); a3 += v3 * b2f(h3.w);
    }
    for (; j < e; j++) {
        int2 p0 = cv[j];
        ushort4 h0 = *(const ushort4*)(H1 + (size_t)p0.x * NHIDS + lane * 4);
        float v0 = __int_as_float(p0.y);
        a0 += v0 * b2f(h0.x); a1 += v0 * b2f(h0.y); a2 += v0 * b2f(h0.z); a3 += v0 * b2f(h0.w);
    }
    float4 bb = *(const float4*)(b1 + lane * 4);
    a0 += bb.x; a1 += bb.y; a2 += bb.z; a3 += bb.w;
    ushort4 o;
    o.x = f2b(a0 > 0.f ? a0 : 0.f);
    o.y = f2b(a1 > 0.f ? a1 : 0.f);
    o.z = f2b(a2 > 0.f ? a2 : 0.f);
    o.w = f2b(a3 > 0.f ? a3 : 0.f);
    *(ushort4*)&AGG[(size_t)r * NHIDS + lane * 4] = o;
}

// ---------------- GEMM2: H2 = bf16(AGG @ W2) via MFMA, padded to 64 cols ----------------
// 256 threads = 4 waves; block covers 256 rows (wave w: rows w*64..w*64+63).
// All 64 output cols per wave = 4 n-tiles; K=256 = 8 chunks of 32. No LDS, no barriers:
// A-frags direct from AGG (16B/lane), B-frags from W2t (32 KB, L1/L2-resident).

__global__ __launch_bounds__(256) void gemm2_kernel(const ushort_t* __restrict__ AGG,
                                                    const ushort_t* __restrict__ W2t,
                                                    ushort_t* __restrict__ H2, int M) {
    int tid  = threadIdx.x;
    int wave = tid >> 6, lane = tid & 63;
    int quad = lane >> 4, ln = lane & 15;
    int m0 = blockIdx.x * 256 + wave * 64;

    floatx4 acc[4][4] = {};
    frag8 zf = {};

#pragma unroll
    for (int k0 = 0; k0 < NHIDS; k0 += 32) {
        frag8 af[4], bf[4];
#pragma unroll
        for (int mt = 0; mt < 4; mt++) {
            int m = m0 + mt * 16 + ln;
            af[mt] = (m < M) ? *(const frag8*)(AGG + (size_t)m * NHIDS + k0 + quad * 8) : zf;
        }
#pragma unroll
        for (int nt = 0; nt < 4; nt++)
            bf[nt] = *(const frag8*)(W2t + (size_t)(nt * 16 + ln) * NHIDS + k0 + quad * 8);
#pragma unroll
        for (int mt = 0; mt < 4; mt++)
#pragma unroll
            for (int nt = 0; nt < 4; nt++)
                acc[mt][nt] = __builtin_amdgcn_mfma_f32_16x16x32_bf16(af[mt], bf[nt], acc[mt][nt], 0, 0, 0);
    }
    // C/D layout: col = ln, row = quad*4 + i
#pragma unroll
    for (int mt = 0; mt < 4; mt++) {
#pragma unroll
        for (int i = 0; i < 4; i++) {
            int m = m0 + mt * 16 + quad * 4 + i;
            if (m < M) {
#pragma unroll
                for (int nt = 0; nt < 4; nt++)
                    H2[(size_t)m * NCLSP + nt * 16 + ln] = f2b(acc[mt][nt][i]);
            }
        }
    }
}

// ---------------- SpMM2: out = A_hat @ H2 + b2, F=40 (padded reads of 64) ----------------
// 2-deep gather unroll.

__global__ __launch_bounds__(256) void spmm2_kernel(const int* __restrict__ row_ptr,
                                                    const int2* __restrict__ cv,
                                                    const ushort_t* __restrict__ H2,
                                                    const float* __restrict__ b2,
                                                    float* __restrict__ out, int N) {
    int wave = threadIdx.x >> 6, lane = threadIdx.x & 63;
    int half = lane >> 5, fl = lane & 31;
    int r = blockIdx.x * 8 + wave * 2 + half;
    if (r >= N) return;
    int s = row_ptr[r], e = row_ptr[r + 1];
    float a0 = 0.f, a1 = 0.f;
    int j = s;
    for (; j + 1 < e; j += 2) {
        int2 p0 = cv[j];
        int2 p1 = cv[j + 1];
        float v0 = __int_as_float(p0.y);
        float v1 = __int_as_float(p1.y);
        uint_t h0 = *(const uint_t*)(H2 + (size_t)p0.x * NCLSP + fl * 2);
        uint_t h1 = *(const uint_t*)(H2 + (size_t)p1.x * NCLSP + fl * 2);
        a0 += v0 * b2f((ushort_t)(h0 & 0xffff));
        a1 += v0 * b2f((ushort_t)(h0 >> 16));
        a0 += v1 * b2f((ushort_t)(h1 & 0xffff));
        a1 += v1 * b2f((ushort_t)(h1 >> 16));
    }
    if (j < e) {
        int2 p = cv[j];
        float v = __int_as_float(p.y);
        uint_t h = *(const uint_t*)(H2 + (size_t)p.x * NCLSP + fl * 2);
        a0 += v * b2f((ushort_t)(h & 0xffff));
        a1 += v * b2f((ushort_t)(h >> 16));
    }
    if (fl < NCLS / 2) {
        float2 o;
        o.x = a0 + b2[fl * 2];
        o.y = a1 + b2[fl * 2 + 1];
        *(float2*)(out + (size_t)r * NCLS + fl * 2) = o;
    }
}

// ---------------- launch ----------------

static inline size_t align256(size_t x) { return (x + 255) & ~(size_t)255; }

extern "C" void kernel_launch(void* const* d_in, const int* in_sizes, int n_in,
                              void* d_out, int out_size, void* d_ws, size_t ws_size,
                              hipStream_t stream) {
    const float* x        = (const float*)d_in[0];
    const float* W1       = (const float*)d_in[1];
    const float* b1       = (const float*)d_in[2];
    const float* W2       = (const float*)d_in[3];
    const float* b2       = (const float*)d_in[4];
    const int*   edge_row = (const int*)d_in[5];
    const int*   edge_col = (const int*)d_in[6];
    const float* edge_val = (const float*)d_in[7];
    float* out = (float*)d_out;

    int N = in_sizes[0] / NFEATS;  // 100000
    int E = in_sizes[5];           // 1700000

    char* w = (char*)d_ws;
    size_t off = 0;
    ushort_t* H1   = (ushort_t*)(w + off); off += align256((size_t)N * NHIDS * 2);
    ushort_t* AGG  = (ushort_t*)(w + off); off += align256((size_t)N * NHIDS * 2);
    ushort_t* H2   = (ushort_t*)(w + off); off += align256((size_t)N * NCLSP * 2);
    ushort_t* W1t  = (ushort_t*)(w + off); off += align256((size_t)NHIDS * NFEATS * 2);
    ushort_t* W2t  = (ushort_t*)(w + off); off += align256((size_t)NCLSP * NHIDS * 2);
    int*      row_ptr = (int*)(w + off); off += align256((size_t)(N + 1) * 4);
    int*      cnt     = (int*)(w + off); off += align256((size_t)N * 4);
    int*      blockSums = (int*)(w + off); off += align256((size_t)SS_T * 4);
    int2*     cv      = (int2*)(w + off); off += align256((size_t)E * 8);

    int scanB = (N + PS_CHUNK - 1) / PS_CHUNK;   // 98 for N=100000 (must be <= SS_T)

    // CSR build + weight conversion
    hipMemsetAsync(cnt, 0, (size_t)N * 4, stream);
    hist_kernel<<<(E + 255) / 256, 256, 0, stream>>>(edge_row, cnt, E);
    convert_w1<<<(NFEATS * NHIDS) / 256, 256, 0, stream>>>(W1, W1t);
    convert_w2<<<(NCLSP * NHIDS) / 256, 256, 0, stream>>>(W2, W2t);
    scan_partial_kernel<<<scanB, PS_T, 0, stream>>>(cnt, blockSums, N);
    scan_sums_kernel<<<1, SS_T, 0, stream>>>(blockSums, scanB);
    scan_finalize_kernel<<<scanB, PS_T, 0, stream>>>(cnt, blockSums, row_ptr, N, E);
    scatter_kernel<<<(E + 255) / 256, 256, 0, stream>>>(edge_row, edge_col, edge_val,
                                                        row_ptr, cnt, cv, E);

    // layer 1
    gemm1_kernel<<<(N + G1_BM - 1) / G1_BM, 256, 0, stream>>>(x, W1t, H1, N);
    spmm1_kernel<<<(N + 3) / 4, 256, 0, stream>>>(row_ptr, cv, H1, b1, AGG, N);

    // layer 2
    gemm2_kernel<<<(N + 255) / 256, 256, 0, stream>>>(AGG, W2t, H2, N);
    spmm2_kernel<<<(N + 7) / 8, 256, 0, stream>>>(row_ptr, cv, H2, b2, out, N);
}